// Round 2
// baseline (28829.199 us; speedup 1.0000x reference)
//
#include <hip/hip_runtime.h>

// ---------------- constants ----------------
#define TT 800
#define BB 32
#define HH 1024
#define G4 4096
#define PRE 256
#define DUR 544
#define XK 800            // PRE + DUR
#define KA 1824           // XK + HH
#define KB 2048           // HH + HH
#define NM 80
#define KP 1568           // HH + DUR

#define SA 1864           // LDS row stride (fp16 elems) for chain-A weights (932 dw, %32==4, 16B aligned)
#define SB 2056           // chain-B (1028 dw, %32==4)
#define SA1 104           // prenet1 dec LDS stride

// ws offsets (bytes)
#define OFF_WIH1B  0ull
#define OFF_WHH1B  6553600ull
#define OFF_WIH2B  14942208ull
#define OFF_WHH2B  23330816ull
#define OFF_WPB    31719424ull
#define OFF_W1B    31970304ull
#define OFF_W2B    32019456ull
#define OFF_XCAT   32150528ull
#define OFF_X1     73110528ull
#define OFF_H1H    86217728ull
#define OFF_H2H    138646528ull
#define OFF_PART1  191075328ull
#define OFF_PART2  191337472ull
#define OFF_FLAGS  191599616ull
#define FLAG_BYTES 217600ull
#define WS_NEEDED  (OFF_FLAGS + FLAG_BYTES)

// dynamic LDS layout for persistent kernel
#define LDS_GBUF_OFF  131584   // float[32*33]
#define LDS_STAT_OFF  135808   // float[64]
#define LDS_RED_OFF   136064   // float[256]
#define LDS_TOTAL     137088

typedef __attribute__((ext_vector_type(8))) _Float16 f16x8;
typedef __attribute__((ext_vector_type(4))) float f32x4;

__device__ __forceinline__ unsigned short f2h(float f) {
    _Float16 h = (_Float16)f;   // v_cvt_f16_f32, round-to-nearest-even
    return __builtin_bit_cast(unsigned short, h);
}
__device__ __forceinline__ float sigf(float x) { return 1.f / (1.f + __expf(-x)); }
__device__ __forceinline__ float tanh_fast(float x) { return 1.f - 2.f / (__expf(2.f * x) + 1.f); }

__device__ __forceinline__ f16x8 ldg8(const unsigned short* p) {
    return *reinterpret_cast<const f16x8*>(p);
}

__device__ __forceinline__ void spin_until(int* p, int target) {
    while (__hip_atomic_load(p, __ATOMIC_RELAXED, __HIP_MEMORY_SCOPE_AGENT) < target)
        __builtin_amdgcn_s_sleep(1);
}

// ---------------- conversion kernels ----------------
__global__ void cvt_kernel(const float* __restrict__ src, unsigned short* __restrict__ dst, int n) {
    for (int i = blockIdx.x * blockDim.x + threadIdx.x; i < n; i += gridDim.x * blockDim.x)
        dst[i] = f2h(src[i]);
}

// W1 [256][80] -> padded fp16 [256][96]
__global__ void cvt_w1_kernel(const float* __restrict__ w1, unsigned short* __restrict__ dst) {
    int i = blockIdx.x * blockDim.x + threadIdx.x;
    if (i >= 256 * 96) return;
    int j = i / 96, m = i % 96;
    dst[i] = (m < 80) ? f2h(w1[j * 80 + m]) : 0;
}

// duration_outputs [B][T][544] -> xcat[t][b][256+e] (fp16)
__global__ void pack_dur_kernel(const float* __restrict__ dur, unsigned short* __restrict__ xcat) {
    int n = TT * BB * DUR;
    for (int i = blockIdx.x * blockDim.x + threadIdx.x; i < n; i += gridDim.x * blockDim.x) {
        int t = i / (BB * DUR);
        int r = i % (BB * DUR);
        int b = r / DUR, e = r % DUR;
        xcat[(size_t)(t * BB + b) * XK + PRE + e] = f2h(dur[(size_t)b * (TT * DUR) + t * DUR + e]);
    }
}

// ---------------- prenet layer 1 (MFMA, K padded 80->96) ----------------
__global__ __launch_bounds__(256) void prenet1_kernel(const float* __restrict__ din,
                                                      const unsigned short* __restrict__ w1b,
                                                      const float* __restrict__ pm1,
                                                      unsigned short* __restrict__ x1b) {
    int t = blockIdx.x;
    __shared__ unsigned short decs[32 * SA1];
    int tid = threadIdx.x;
    for (int idx = tid; idx < 32 * 96; idx += 256) {
        int b = idx / 96, m = idx % 96;
        float v = (m < 80 && t > 0) ? din[(size_t)b * 64000 + m * 800 + (t - 1)] : 0.f;
        decs[b * SA1 + m] = f2h(v);
    }
    __syncthreads();
    int lane = tid & 63, wid = tid >> 6;
    int l15 = lane & 15, quad = lane >> 4;
    int kblk = quad * 8;
    #pragma unroll
    for (int i = 0; i < 8; i++) {
        int tt = wid * 8 + i;           // 32 tiles: Mt = tt&1, Nt = tt>>1
        int Mt = tt & 1, Nt = tt >> 1;
        f32x4 acc = {0.f, 0.f, 0.f, 0.f};
        int arow = (Mt * 16 + l15) * SA1 + kblk;
        int brow = (Nt * 16 + l15) * 96 + kblk;
        #pragma unroll
        for (int kk = 0; kk < 3; kk++) {
            f16x8 a = *reinterpret_cast<const f16x8*>(&decs[arow + kk * 32]);
            f16x8 b = ldg8(w1b + brow + kk * 32);
            acc = __builtin_amdgcn_mfma_f32_16x16x32_f16(a, b, acc, 0, 0, 0);
        }
        int n = Nt * 16 + l15;
        #pragma unroll
        for (int r = 0; r < 4; r++) {
            int b_row = Mt * 16 + quad * 4 + r;
            float v = fmaxf(acc[r], 0.f) * pm1[(size_t)(t * BB + b_row) * PRE + n];
            x1b[(size_t)(t * BB + b_row) * PRE + n] = f2h(v);
        }
    }
}

// ---------------- prenet layer 2 (MFMA) ----------------
__global__ __launch_bounds__(256) void prenet2_kernel(const unsigned short* __restrict__ x1b,
                                                      const unsigned short* __restrict__ w2b,
                                                      const float* __restrict__ pm2,
                                                      unsigned short* __restrict__ xcat) {
    int t = blockIdx.x;
    int tid = threadIdx.x;
    int lane = tid & 63, wid = tid >> 6;
    int l15 = lane & 15, quad = lane >> 4;
    int kblk = quad * 8;
    #pragma unroll
    for (int i = 0; i < 8; i++) {
        int tt = wid * 8 + i;
        int Mt = tt & 1, Nt = tt >> 1;
        f32x4 acc = {0.f, 0.f, 0.f, 0.f};
        const unsigned short* arow = x1b + (size_t)(t * BB + Mt * 16 + l15) * PRE + kblk;
        const unsigned short* brow = w2b + (size_t)(Nt * 16 + l15) * PRE + kblk;
        #pragma unroll
        for (int kk = 0; kk < 8; kk++) {
            f16x8 a = ldg8(arow + kk * 32);
            f16x8 b = ldg8(brow + kk * 32);
            acc = __builtin_amdgcn_mfma_f32_16x16x32_f16(a, b, acc, 0, 0, 0);
        }
        int n = Nt * 16 + l15;
        #pragma unroll
        for (int r = 0; r < 4; r++) {
            int b_row = Mt * 16 + quad * 4 + r;
            float v = fmaxf(acc[r], 0.f) * pm2[(size_t)(t * BB + b_row) * PRE + n];
            xcat[(size_t)(t * BB + b_row) * XK + n] = f2h(v);
        }
    }
}

// ---------------- persistent recurrence kernel ----------------
__global__ __launch_bounds__(256, 1) void persistent_kernel(
    const unsigned short* __restrict__ xcat,
    const unsigned short* __restrict__ wih1b, const unsigned short* __restrict__ whh1b,
    const unsigned short* __restrict__ wih2b, const unsigned short* __restrict__ whh2b,
    const float* __restrict__ b1, const float* __restrict__ g1, const float* __restrict__ be1,
    const float* __restrict__ b2, const float* __restrict__ g2, const float* __restrict__ be2,
    const float* __restrict__ dm1, const float* __restrict__ dm2,
    unsigned short* __restrict__ h1h, unsigned short* __restrict__ h2h,
    float* __restrict__ part1, float* __restrict__ part2,
    int* __restrict__ flags) {

    extern __shared__ char smem[];
    unsigned short* W = (unsigned short*)smem;
    float* gbuf = (float*)(smem + LDS_GBUF_OFF);    // [32][33]
    float* stat = (float*)(smem + LDS_STAT_OFF);    // [64]
    float* red  = (float*)(smem + LDS_RED_OFF);     // [256]

    int wg = blockIdx.x;
    bool isA = wg < 128;
    int w = isA ? wg : wg - 128;
    int tid = threadIdx.x;
    int lane = tid & 63, wid = tid >> 6;
    int l15 = lane & 15, quad = lane >> 4;
    int Mt = wid >> 1, Nt = wid & 1;
    int kblk = quad * 8;

    // flag pointers
    int* r_stats1 = flags;
    int* r_h1     = flags + 800;
    int* r_stats2 = flags + 1600;
    int* r_h2     = flags + 2400;
    int* gbase    = flags + 3200;
    int* g_stats1 = gbase;
    int* g_h1     = gbase + 12800;
    int* g_stats2 = gbase + 25600;
    int* g_h2     = gbase + 38400;

    int* r_stats = isA ? r_stats1 : r_stats2;
    int* g_stats = isA ? g_stats1 : g_stats2;
    int* r_hmy   = isA ? r_h1 : r_h2;
    int* g_hmy   = isA ? g_h1 : g_h2;
    float* part  = isA ? part1 : part2;
    int gidx = w >> 3;   // 16 groups of 8

    // load weight slice into LDS
    if (isA) {
        for (int idx = tid; idx < 32 * KA; idx += 256) {
            int r = idx / KA, k = idx % KA;
            int grow = (r >> 3) * HH + w * 8 + (r & 7);
            W[r * SA + k] = (k < XK) ? wih1b[(size_t)grow * XK + k]
                                     : whh1b[(size_t)grow * HH + (k - XK)];
        }
    } else {
        for (int idx = tid; idx < 32 * KB; idx += 256) {
            int r = idx / KB, k = idx % KB;
            int grow = (r >> 3) * HH + w * 8 + (r & 7);
            W[r * SB + k] = (k < HH) ? wih2b[(size_t)grow * HH + k]
                                     : whh2b[(size_t)grow * HH + (k - HH)];
        }
    }

    // per-lane constants for epilogue (bias per gate-row)
    int n_loc = Nt * 16 + l15;
    int gate_n = (n_loc >> 3) * HH + w * 8 + (n_loc & 7);
    float bv = isA ? b1[gate_n] : b2[gate_n];

    // pointwise thread constants
    int pb = tid & 31, pu = tid >> 5;
    int unit = w * 8 + pu;
    float g1v[4], bev[4];
    {
        const float* gs = isA ? g1 : g2;
        const float* bs = isA ? be1 : be2;
        #pragma unroll
        for (int g = 0; g < 4; g++) { g1v[g] = gs[g * HH + unit]; bev[g] = bs[g * HH + unit]; }
    }
    const float* dms = isA ? dm1 : dm2;
    unsigned short* hout = isA ? h1h : h2h;
    float creg = 0.f;
    __syncthreads();

    for (int t = 0; t < TT; t++) {
        f32x4 acc = {0.f, 0.f, 0.f, 0.f};
        int b_row = Mt * 16 + l15;

        if (isA) {
            // x-part (no dependency on h1[t-1])
            const unsigned short* xrow = xcat + (size_t)(t * BB + b_row) * XK + kblk;
            #pragma unroll
            for (int kk = 0; kk < 25; kk++) {
                f16x8 a = ldg8(xrow + kk * 32);
                f16x8 b = *reinterpret_cast<const f16x8*>(&W[n_loc * SA + kk * 32 + kblk]);
                acc = __builtin_amdgcn_mfma_f32_16x16x32_f16(a, b, acc, 0, 0, 0);
            }
            if (t > 0) {
                if (tid == 0) { spin_until(&r_h1[t - 1], 16); __threadfence(); }
                __syncthreads();
                const unsigned short* hrow = h1h + (size_t)((t - 1) * BB + b_row) * HH + kblk;
                #pragma unroll
                for (int kk = 0; kk < 32; kk++) {
                    f16x8 a = ldg8(hrow + kk * 32);
                    f16x8 b = *reinterpret_cast<const f16x8*>(&W[n_loc * SA + XK + kk * 32 + kblk]);
                    acc = __builtin_amdgcn_mfma_f32_16x16x32_f16(a, b, acc, 0, 0, 0);
                }
            }
        } else {
            // h2-part first (depends on own chain's previous step)
            if (t > 0) {
                if (tid == 0) { spin_until(&r_h2[t - 1], 16); __threadfence(); }
                __syncthreads();
                const unsigned short* hrow = h2h + (size_t)((t - 1) * BB + b_row) * HH + kblk;
                #pragma unroll
                for (int kk = 0; kk < 32; kk++) {
                    f16x8 a = ldg8(hrow + kk * 32);
                    f16x8 b = *reinterpret_cast<const f16x8*>(&W[n_loc * SB + HH + kk * 32 + kblk]);
                    acc = __builtin_amdgcn_mfma_f32_16x16x32_f16(a, b, acc, 0, 0, 0);
                }
            }
            // h1-part (depends on chain A's step t)
            if (tid == 0) { spin_until(&r_h1[t], 16); __threadfence(); }
            __syncthreads();
            const unsigned short* hrow = h1h + (size_t)(t * BB + b_row) * HH + kblk;
            #pragma unroll
            for (int kk = 0; kk < 32; kk++) {
                f16x8 a = ldg8(hrow + kk * 32);
                f16x8 b = *reinterpret_cast<const f16x8*>(&W[n_loc * SB + kk * 32 + kblk]);
                acc = __builtin_amdgcn_mfma_f32_16x16x32_f16(a, b, acc, 0, 0, 0);
            }
        }

        // epilogue into LDS gate buffer (+bias, pre-LN)
        #pragma unroll
        for (int r = 0; r < 4; r++) {
            int m = Mt * 16 + quad * 4 + r;
            gbuf[n_loc * 33 + m] = acc[r] + bv;
        }
        __syncthreads();

        // LN partials (sum, sumsq over this WG's 32 gate rows, per batch)
        if (tid < 64) {
            int b = tid & 31, st = tid >> 5;
            float s = 0.f;
            #pragma unroll 8
            for (int n = 0; n < 32; n++) { float v = gbuf[n * 33 + b]; s += st ? v * v : v; }
            part[(size_t)(t & 7) * 8192 + w * 64 + tid] = s;
        }
        __syncthreads();
        if (tid == 0) {
            __threadfence();
            int old = __hip_atomic_fetch_add(&g_stats[t * 16 + gidx], 1, __ATOMIC_RELAXED, __HIP_MEMORY_SCOPE_AGENT);
            if (old == 7)
                __hip_atomic_fetch_add(&r_stats[t], 1, __ATOMIC_RELAXED, __HIP_MEMORY_SCOPE_AGENT);
            spin_until(&r_stats[t], 16);
            __threadfence();
        }
        __syncthreads();

        // reduce 128 partials -> stats[64]
        {
            int bs = tid & 63, wp = tid >> 6;
            float s = 0.f;
            const float* pp = part + (size_t)(t & 7) * 8192;
            #pragma unroll 8
            for (int j = 0; j < 32; j++) s += pp[(wp + j * 4) * 64 + bs];
            red[tid] = s;
        }
        __syncthreads();
        if (tid < 64) stat[tid] = red[tid] + red[64 + tid] + red[128 + tid] + red[192 + tid];
        __syncthreads();

        // pointwise: LN -> LSTM cell -> dropout -> publish h (fp16)
        {
            float mean = stat[pb] * (1.f / 4096.f);
            float var = stat[32 + pb] * (1.f / 4096.f) - mean * mean;
            float rs = rsqrtf(var + 1e-5f);
            float z[4];
            #pragma unroll
            for (int g = 0; g < 4; g++)
                z[g] = (gbuf[(g * 8 + pu) * 33 + pb] - mean) * rs * g1v[g] + bev[g];
            float iv = sigf(z[0]), fv = sigf(z[1]), gv = tanh_fast(z[2]), ov = sigf(z[3]);
            creg = fv * creg + iv * gv;
            float h = ov * tanh_fast(creg);
            h *= dms[(size_t)(t * BB + pb) * HH + unit];
            hout[(size_t)(t * BB + pb) * HH + unit] = f2h(h);
        }
        __syncthreads();   // drain h stores (barrier waits vmcnt)
        if (tid == 0) {
            __threadfence();
            int old = __hip_atomic_fetch_add(&g_hmy[t * 16 + gidx], 1, __ATOMIC_RELAXED, __HIP_MEMORY_SCOPE_AGENT);
            if (old == 7)
                __hip_atomic_fetch_add(&r_hmy[t], 1, __ATOMIC_RELAXED, __HIP_MEMORY_SCOPE_AGENT);
        }
        // no barrier needed here: next iteration's consumers spin on flags
    }
}

// ---------------- final projection ----------------
// out[b][mel][t] = concat(h2[t][b], dur[t][b]) @ Wp^T + bp
__global__ __launch_bounds__(256) void projection_kernel(const unsigned short* __restrict__ h2h,
                                                         const unsigned short* __restrict__ xcat,
                                                         const unsigned short* __restrict__ wpb,
                                                         const float* __restrict__ bp,
                                                         float* __restrict__ out) {
    int t = blockIdx.x;
    int tid = threadIdx.x;
    int lane = tid & 63, wid = tid >> 6;
    int l15 = lane & 15, quad = lane >> 4;
    int kblk = quad * 8;
    #pragma unroll
    for (int i = 0; i < 3; i++) {
        int tt = wid + i * 4;
        if (tt >= 10) break;          // 2 Mt x 5 Nt tiles
        int Mt = tt & 1, Nt = tt >> 1;
        f32x4 acc = {0.f, 0.f, 0.f, 0.f};
        int b_row = Mt * 16 + l15;
        const unsigned short* h2row = h2h + (size_t)(t * BB + b_row) * HH + kblk;
        const unsigned short* brow = wpb + (size_t)(Nt * 16 + l15) * KP + kblk;
        #pragma unroll
        for (int kk = 0; kk < 32; kk++) {
            f16x8 a = ldg8(h2row + kk * 32);
            f16x8 b = ldg8(brow + kk * 32);
            acc = __builtin_amdgcn_mfma_f32_16x16x32_f16(a, b, acc, 0, 0, 0);
        }
        const unsigned short* drow = xcat + (size_t)(t * BB + b_row) * XK + PRE + kblk;
        #pragma unroll
        for (int kk = 0; kk < 17; kk++) {
            f16x8 a = ldg8(drow + kk * 32);
            f16x8 b = ldg8(brow + HH + kk * 32);
            acc = __builtin_amdgcn_mfma_f32_16x16x32_f16(a, b, acc, 0, 0, 0);
        }
        int mel = Nt * 16 + l15;
        float bpv = bp[mel];
        #pragma unroll
        for (int r = 0; r < 4; r++) {
            int b = Mt * 16 + quad * 4 + r;
            out[(size_t)b * 64000 + mel * 800 + t] = acc[r] + bpv;
        }
    }
}

// ---------------- launch ----------------
extern "C" void kernel_launch(void* const* d_in, const int* in_sizes, int n_in,
                              void* d_out, int out_size, void* d_ws, size_t ws_size,
                              hipStream_t stream) {
    (void)in_sizes; (void)n_in; (void)out_size;
    const float* dur  = (const float*)d_in[0];
    const float* din  = (const float*)d_in[1];
    const float* W1   = (const float*)d_in[3];
    const float* W2   = (const float*)d_in[4];
    const float* Wih1 = (const float*)d_in[5];
    const float* Whh1 = (const float*)d_in[6];
    const float* b1   = (const float*)d_in[7];
    const float* g1   = (const float*)d_in[8];
    const float* be1  = (const float*)d_in[9];
    const float* Wih2 = (const float*)d_in[10];
    const float* Whh2 = (const float*)d_in[11];
    const float* b2   = (const float*)d_in[12];
    const float* g2   = (const float*)d_in[13];
    const float* be2  = (const float*)d_in[14];
    const float* Wp   = (const float*)d_in[15];
    const float* bp   = (const float*)d_in[16];
    const float* pm1  = (const float*)d_in[17];
    const float* pm2  = (const float*)d_in[18];
    const float* dm1  = (const float*)d_in[19];
    const float* dm2  = (const float*)d_in[20];
    float* out = (float*)d_out;
    char* ws = (char*)d_ws;
    if (ws_size < WS_NEEDED) return;   // will fail validation visibly

    unsigned short* wih1b = (unsigned short*)(ws + OFF_WIH1B);
    unsigned short* whh1b = (unsigned short*)(ws + OFF_WHH1B);
    unsigned short* wih2b = (unsigned short*)(ws + OFF_WIH2B);
    unsigned short* whh2b = (unsigned short*)(ws + OFF_WHH2B);
    unsigned short* wpb   = (unsigned short*)(ws + OFF_WPB);
    unsigned short* w1b   = (unsigned short*)(ws + OFF_W1B);
    unsigned short* w2b   = (unsigned short*)(ws + OFF_W2B);
    unsigned short* xcat  = (unsigned short*)(ws + OFF_XCAT);
    unsigned short* x1b   = (unsigned short*)(ws + OFF_X1);
    unsigned short* h1h   = (unsigned short*)(ws + OFF_H1H);
    unsigned short* h2h   = (unsigned short*)(ws + OFF_H2H);
    float* part1 = (float*)(ws + OFF_PART1);
    float* part2 = (float*)(ws + OFF_PART2);
    int* flags   = (int*)(ws + OFF_FLAGS);

    hipMemsetAsync(flags, 0, FLAG_BYTES, stream);

    int thr = 256;
    cvt_kernel<<<4096, thr, 0, stream>>>(Wih1, wih1b, G4 * XK);
    cvt_kernel<<<4096, thr, 0, stream>>>(Whh1, whh1b, G4 * HH);
    cvt_kernel<<<4096, thr, 0, stream>>>(Wih2, wih2b, G4 * HH);
    cvt_kernel<<<4096, thr, 0, stream>>>(Whh2, whh2b, G4 * HH);
    cvt_kernel<<<512,  thr, 0, stream>>>(Wp, wpb, NM * KP);
    cvt_w1_kernel<<<(256 * 96 + 255) / 256, thr, 0, stream>>>(W1, w1b);
    cvt_kernel<<<256,  thr, 0, stream>>>(W2, w2b, 256 * 256);

    prenet1_kernel<<<TT, thr, 0, stream>>>(din, w1b, pm1, x1b);
    prenet2_kernel<<<TT, thr, 0, stream>>>(x1b, w2b, pm2, xcat);
    pack_dur_kernel<<<8192, thr, 0, stream>>>(dur, xcat);

    hipFuncSetAttribute((const void*)persistent_kernel,
                        hipFuncAttributeMaxDynamicSharedMemorySize, LDS_TOTAL);
    persistent_kernel<<<256, thr, LDS_TOTAL, stream>>>(
        xcat, wih1b, whh1b, wih2b, whh2b,
        b1, g1, be1, b2, g2, be2, dm1, dm2,
        h1h, h2h, part1, part2, flags);

    projection_kernel<<<TT, thr, 0, stream>>>(h2h, xcat, wpb, bp, out);
}

// Round 3
// 20175.723 us; speedup vs baseline: 1.4289x; 1.4289x over previous
//
#include <hip/hip_runtime.h>

// ---------------- constants ----------------
#define TT 800
#define BB 32
#define HH 1024
#define G4 4096
#define PRE 256
#define DUR 544
#define XK 800            // PRE + DUR
#define KA 1824           // XK + HH
#define KB 2048           // HH + HH
#define NM 80
#define KP 1568           // HH + DUR

#define SA 1864           // LDS row stride (fp16 elems) for chain-A weights
#define SB 2056           // chain-B
#define SA1 104           // prenet1 dec LDS stride

// ws offsets (bytes)
#define OFF_WIH1B  0ull
#define OFF_WHH1B  6553600ull
#define OFF_WIH2B  14942208ull
#define OFF_WHH2B  23330816ull
#define OFF_WPB    31719424ull
#define OFF_W1B    31970304ull
#define OFF_W2B    32019456ull
#define OFF_XCAT   32150528ull
#define OFF_X1     73110528ull
#define OFF_H1H    86217728ull
#define OFF_H2H    138646528ull
#define OFF_PART1  191075328ull
#define OFF_PART2  191337472ull
#define OFF_FLAGS  191599616ull
#define FLAG_BYTES 217600ull
#define WS_NEEDED  (OFF_FLAGS + FLAG_BYTES)

// dynamic LDS layout for persistent kernel
#define LDS_GBUF_OFF  131584   // float[32*33]
#define LDS_STAT_OFF  135808   // float[64]
#define LDS_RED_OFF   136064   // float[256]
#define LDS_TOTAL     137088

typedef __attribute__((ext_vector_type(8))) _Float16 f16x8;
typedef __attribute__((ext_vector_type(4))) float f32x4;

__device__ __forceinline__ unsigned short f2h(float f) {
    _Float16 h = (_Float16)f;   // v_cvt_f16_f32, RNE
    return __builtin_bit_cast(unsigned short, h);
}
__device__ __forceinline__ float sigf(float x) { return 1.f / (1.f + __expf(-x)); }
__device__ __forceinline__ float tanh_fast(float x) { return 1.f - 2.f / (__expf(2.f * x) + 1.f); }

__device__ __forceinline__ f16x8 ldg8(const unsigned short* p) {
    return *reinterpret_cast<const f16x8*>(p);
}

// coherent (IF$-direct, no cache maintenance) 16B h-fragment load: 2x 8B relaxed agent atomics
__device__ __forceinline__ f16x8 ld_h16(const unsigned long long* p) {
    union { unsigned long long u[2]; f16x8 v; } x;
    x.u[0] = __hip_atomic_load(p,     __ATOMIC_RELAXED, __HIP_MEMORY_SCOPE_AGENT);
    x.u[1] = __hip_atomic_load(p + 1, __ATOMIC_RELAXED, __HIP_MEMORY_SCOPE_AGENT);
    return x.v;
}

__device__ __forceinline__ void spin_until(int* p, int target) {
    while (__hip_atomic_load(p, __ATOMIC_RELAXED, __HIP_MEMORY_SCOPE_AGENT) < target)
        __builtin_amdgcn_s_sleep(1);
}

// wait vmcnt(0) only: vmcnt bits[3:0]+[15:14]=0, expcnt[6:4]=7, lgkmcnt[11:8]=0xF
#define WAIT_VM0() __builtin_amdgcn_s_waitcnt(0x0F70)

// ---------------- conversion kernels ----------------
__global__ void cvt_kernel(const float* __restrict__ src, unsigned short* __restrict__ dst, int n) {
    for (int i = blockIdx.x * blockDim.x + threadIdx.x; i < n; i += gridDim.x * blockDim.x)
        dst[i] = f2h(src[i]);
}

__global__ void cvt_w1_kernel(const float* __restrict__ w1, unsigned short* __restrict__ dst) {
    int i = blockIdx.x * blockDim.x + threadIdx.x;
    if (i >= 256 * 96) return;
    int j = i / 96, m = i % 96;
    dst[i] = (m < 80) ? f2h(w1[j * 80 + m]) : 0;
}

__global__ void pack_dur_kernel(const float* __restrict__ dur, unsigned short* __restrict__ xcat) {
    int n = TT * BB * DUR;
    for (int i = blockIdx.x * blockDim.x + threadIdx.x; i < n; i += gridDim.x * blockDim.x) {
        int t = i / (BB * DUR);
        int r = i % (BB * DUR);
        int b = r / DUR, e = r % DUR;
        xcat[(size_t)(t * BB + b) * XK + PRE + e] = f2h(dur[(size_t)b * (TT * DUR) + t * DUR + e]);
    }
}

// ---------------- prenet layer 1 ----------------
__global__ __launch_bounds__(256) void prenet1_kernel(const float* __restrict__ din,
                                                      const unsigned short* __restrict__ w1b,
                                                      const float* __restrict__ pm1,
                                                      unsigned short* __restrict__ x1b) {
    int t = blockIdx.x;
    __shared__ unsigned short decs[32 * SA1];
    int tid = threadIdx.x;
    for (int idx = tid; idx < 32 * 96; idx += 256) {
        int b = idx / 96, m = idx % 96;
        float v = (m < 80 && t > 0) ? din[(size_t)b * 64000 + m * 800 + (t - 1)] : 0.f;
        decs[b * SA1 + m] = f2h(v);
    }
    __syncthreads();
    int lane = tid & 63, wid = tid >> 6;
    int l15 = lane & 15, quad = lane >> 4;
    int kblk = quad * 8;
    #pragma unroll
    for (int i = 0; i < 8; i++) {
        int tt = wid * 8 + i;
        int Mt = tt & 1, Nt = tt >> 1;
        f32x4 acc = {0.f, 0.f, 0.f, 0.f};
        int arow = (Mt * 16 + l15) * SA1 + kblk;
        int brow = (Nt * 16 + l15) * 96 + kblk;
        #pragma unroll
        for (int kk = 0; kk < 3; kk++) {
            f16x8 a = *reinterpret_cast<const f16x8*>(&decs[arow + kk * 32]);
            f16x8 b = ldg8(w1b + brow + kk * 32);
            acc = __builtin_amdgcn_mfma_f32_16x16x32_f16(a, b, acc, 0, 0, 0);
        }
        int n = Nt * 16 + l15;
        #pragma unroll
        for (int r = 0; r < 4; r++) {
            int b_row = Mt * 16 + quad * 4 + r;
            float v = fmaxf(acc[r], 0.f) * pm1[(size_t)(t * BB + b_row) * PRE + n];
            x1b[(size_t)(t * BB + b_row) * PRE + n] = f2h(v);
        }
    }
}

// ---------------- prenet layer 2 ----------------
__global__ __launch_bounds__(256) void prenet2_kernel(const unsigned short* __restrict__ x1b,
                                                      const unsigned short* __restrict__ w2b,
                                                      const float* __restrict__ pm2,
                                                      unsigned short* __restrict__ xcat) {
    int t = blockIdx.x;
    int tid = threadIdx.x;
    int lane = tid & 63, wid = tid >> 6;
    int l15 = lane & 15, quad = lane >> 4;
    int kblk = quad * 8;
    #pragma unroll
    for (int i = 0; i < 8; i++) {
        int tt = wid * 8 + i;
        int Mt = tt & 1, Nt = tt >> 1;
        f32x4 acc = {0.f, 0.f, 0.f, 0.f};
        const unsigned short* arow = x1b + (size_t)(t * BB + Mt * 16 + l15) * PRE + kblk;
        const unsigned short* brow = w2b + (size_t)(Nt * 16 + l15) * PRE + kblk;
        #pragma unroll
        for (int kk = 0; kk < 8; kk++) {
            f16x8 a = ldg8(arow + kk * 32);
            f16x8 b = ldg8(brow + kk * 32);
            acc = __builtin_amdgcn_mfma_f32_16x16x32_f16(a, b, acc, 0, 0, 0);
        }
        int n = Nt * 16 + l15;
        #pragma unroll
        for (int r = 0; r < 4; r++) {
            int b_row = Mt * 16 + quad * 4 + r;
            float v = fmaxf(acc[r], 0.f) * pm2[(size_t)(t * BB + b_row) * PRE + n];
            xcat[(size_t)(t * BB + b_row) * XK + n] = f2h(v);
        }
    }
}

// ---------------- persistent recurrence kernel ----------------
__global__ __launch_bounds__(256, 1) void persistent_kernel(
    const unsigned short* __restrict__ xcat,
    const unsigned short* __restrict__ wih1b, const unsigned short* __restrict__ whh1b,
    const unsigned short* __restrict__ wih2b, const unsigned short* __restrict__ whh2b,
    const float* __restrict__ b1, const float* __restrict__ g1, const float* __restrict__ be1,
    const float* __restrict__ b2, const float* __restrict__ g2, const float* __restrict__ be2,
    const float* __restrict__ dm1, const float* __restrict__ dm2,
    unsigned short* __restrict__ h1h, unsigned short* __restrict__ h2h,
    float* __restrict__ part1, float* __restrict__ part2,
    int* __restrict__ flags) {

    extern __shared__ char smem[];
    unsigned short* W = (unsigned short*)smem;
    float* gbuf = (float*)(smem + LDS_GBUF_OFF);    // [32][33]
    float* stat = (float*)(smem + LDS_STAT_OFF);    // [64]
    float* red  = (float*)(smem + LDS_RED_OFF);     // [256]
    unsigned short* hpack = (unsigned short*)red;   // reuse (512 B) for h repack

    int wg = blockIdx.x;
    bool isA = wg < 128;
    int w = isA ? wg : wg - 128;
    int tid = threadIdx.x;
    int lane = tid & 63, wid = tid >> 6;
    int l15 = lane & 15, quad = lane >> 4;
    int Mt = wid >> 1, Nt = wid & 1;
    int kblk = quad * 8;

    // flag pointers
    int* r_h1     = flags + 800;
    int* gbase    = flags + 3200;
    int* r_stats  = isA ? flags : (flags + 1600);
    int* r_hmy    = isA ? (flags + 800) : (flags + 2400);
    int* g_stats  = isA ? gbase : (gbase + 25600);
    int* g_hmy    = isA ? (gbase + 12800) : (gbase + 38400);
    float* part   = isA ? part1 : part2;
    int gidx = w >> 3;   // 16 groups of 8

    // load weight slice into LDS (plain cached loads; written by prior dispatches)
    if (isA) {
        for (int idx = tid; idx < 32 * KA; idx += 256) {
            int r = idx / KA, k = idx % KA;
            int grow = (r >> 3) * HH + w * 8 + (r & 7);
            W[r * SA + k] = (k < XK) ? wih1b[(size_t)grow * XK + k]
                                     : whh1b[(size_t)grow * HH + (k - XK)];
        }
    } else {
        for (int idx = tid; idx < 32 * KB; idx += 256) {
            int r = idx / KB, k = idx % KB;
            int grow = (r >> 3) * HH + w * 8 + (r & 7);
            W[r * SB + k] = (k < HH) ? wih2b[(size_t)grow * HH + k]
                                     : whh2b[(size_t)grow * HH + (k - HH)];
        }
    }

    int n_loc = Nt * 16 + l15;
    int gate_n = (n_loc >> 3) * HH + w * 8 + (n_loc & 7);
    float bv = isA ? b1[gate_n] : b2[gate_n];

    int pb = tid & 31, pu = tid >> 5;
    int unit = w * 8 + pu;
    float g1v[4], bev[4];
    {
        const float* gs = isA ? g1 : g2;
        const float* bs = isA ? be1 : be2;
        #pragma unroll
        for (int g = 0; g < 4; g++) { g1v[g] = gs[g * HH + unit]; bev[g] = bs[g * HH + unit]; }
    }
    const float* dms = isA ? dm1 : dm2;
    unsigned short* hout = isA ? h1h : h2h;
    float creg = 0.f;
    __syncthreads();

    for (int t = 0; t < TT; t++) {
        f32x4 acc = {0.f, 0.f, 0.f, 0.f};
        int b_row = Mt * 16 + l15;

        if (isA) {
            // x-part (no dependency on h1[t-1]) — plain cached loads, L2 stays warm
            const unsigned short* xrow = xcat + (size_t)(t * BB + b_row) * XK + kblk;
            #pragma unroll
            for (int kk = 0; kk < 25; kk++) {
                f16x8 a = ldg8(xrow + kk * 32);
                f16x8 b = *reinterpret_cast<const f16x8*>(&W[n_loc * SA + kk * 32 + kblk]);
                acc = __builtin_amdgcn_mfma_f32_16x16x32_f16(a, b, acc, 0, 0, 0);
            }
            if (t > 0) {
                if (tid == 0) spin_until(&r_hmy[t - 1], 16);
                __syncthreads();
                const unsigned long long* hrow = (const unsigned long long*)
                    (h1h + (size_t)((t - 1) * BB + b_row) * HH + kblk);
                #pragma unroll
                for (int kk = 0; kk < 32; kk++) {
                    f16x8 a = ld_h16(hrow + kk * 8);
                    f16x8 b = *reinterpret_cast<const f16x8*>(&W[n_loc * SA + XK + kk * 32 + kblk]);
                    acc = __builtin_amdgcn_mfma_f32_16x16x32_f16(a, b, acc, 0, 0, 0);
                }
            }
        } else {
            if (t > 0) {
                if (tid == 0) spin_until(&r_hmy[t - 1], 16);
                __syncthreads();
                const unsigned long long* hrow = (const unsigned long long*)
                    (h2h + (size_t)((t - 1) * BB + b_row) * HH + kblk);
                #pragma unroll
                for (int kk = 0; kk < 32; kk++) {
                    f16x8 a = ld_h16(hrow + kk * 8);
                    f16x8 b = *reinterpret_cast<const f16x8*>(&W[n_loc * SB + HH + kk * 32 + kblk]);
                    acc = __builtin_amdgcn_mfma_f32_16x16x32_f16(a, b, acc, 0, 0, 0);
                }
            }
            if (tid == 0) spin_until(&r_h1[t], 16);
            __syncthreads();
            const unsigned long long* hrow = (const unsigned long long*)
                (h1h + (size_t)(t * BB + b_row) * HH + kblk);
            #pragma unroll
            for (int kk = 0; kk < 32; kk++) {
                f16x8 a = ld_h16(hrow + kk * 8);
                f16x8 b = *reinterpret_cast<const f16x8*>(&W[n_loc * SB + kk * 32 + kblk]);
                acc = __builtin_amdgcn_mfma_f32_16x16x32_f16(a, b, acc, 0, 0, 0);
            }
        }

        // epilogue into LDS gate buffer (+bias, pre-LN)
        #pragma unroll
        for (int r = 0; r < 4; r++) {
            int m = Mt * 16 + quad * 4 + r;
            gbuf[n_loc * 33 + m] = acc[r] + bv;
        }
        __syncthreads();

        // LN partials (wave 0 only -> its vmcnt covers the coherent stores)
        if (tid < 64) {
            int b = tid & 31, st = tid >> 5;
            float s = 0.f;
            #pragma unroll 8
            for (int n = 0; n < 32; n++) { float v = gbuf[n * 33 + b]; s += st ? v * v : v; }
            __hip_atomic_store(&part[(size_t)(t & 7) * 8192 + w * 64 + tid], s,
                               __ATOMIC_RELAXED, __HIP_MEMORY_SCOPE_AGENT);
        }
        if (tid == 0) {
            WAIT_VM0();   // drain wave-0 coherent stores before signaling
            int old = __hip_atomic_fetch_add(&g_stats[t * 16 + gidx], 1,
                                             __ATOMIC_RELAXED, __HIP_MEMORY_SCOPE_AGENT);
            if (old == 7)
                __hip_atomic_fetch_add(&r_stats[t], 1,
                                       __ATOMIC_RELAXED, __HIP_MEMORY_SCOPE_AGENT);
            spin_until(&r_stats[t], 16);
        }
        __syncthreads();

        // reduce 128 partials -> stats[64] (coherent loads, no cache maintenance)
        {
            int bs = tid & 63, wp = tid >> 6;
            float s = 0.f;
            const float* pp = part + (size_t)(t & 7) * 8192;
            #pragma unroll
            for (int j = 0; j < 32; j++)
                s += __hip_atomic_load(&pp[(wp + j * 4) * 64 + bs],
                                       __ATOMIC_RELAXED, __HIP_MEMORY_SCOPE_AGENT);
            red[tid] = s;
        }
        __syncthreads();
        if (tid < 64) stat[tid] = red[tid] + red[64 + tid] + red[128 + tid] + red[192 + tid];
        __syncthreads();

        // pointwise: LN -> LSTM cell -> dropout -> repack h into LDS
        {
            float mean = stat[pb] * (1.f / 4096.f);
            float var = stat[32 + pb] * (1.f / 4096.f) - mean * mean;
            float rs = rsqrtf(var + 1e-5f);
            float z[4];
            #pragma unroll
            for (int g = 0; g < 4; g++)
                z[g] = (gbuf[(g * 8 + pu) * 33 + pb] - mean) * rs * g1v[g] + bev[g];
            float iv = sigf(z[0]), fv = sigf(z[1]), gv = tanh_fast(z[2]), ov = sigf(z[3]);
            creg = fv * creg + iv * gv;
            float h = ov * tanh_fast(creg);
            h *= dms[(size_t)(t * BB + pb) * HH + unit];
            hpack[pb * 8 + pu] = f2h(h);
        }
        __syncthreads();

        // publish h: wave 0 stores 64x 8B coherent, then signals
        if (tid < 64) {
            int b = tid >> 1, half = tid & 1;
            unsigned long long v = *(const unsigned long long*)((const char*)hpack + tid * 8);
            __hip_atomic_store((unsigned long long*)(hout + (size_t)(t * BB + b) * HH + w * 8 + half * 4),
                               v, __ATOMIC_RELAXED, __HIP_MEMORY_SCOPE_AGENT);
        }
        if (tid == 0) {
            WAIT_VM0();
            int old = __hip_atomic_fetch_add(&g_hmy[t * 16 + gidx], 1,
                                             __ATOMIC_RELAXED, __HIP_MEMORY_SCOPE_AGENT);
            if (old == 7)
                __hip_atomic_fetch_add(&r_hmy[t], 1,
                                       __ATOMIC_RELAXED, __HIP_MEMORY_SCOPE_AGENT);
        }
        // next iteration's consumers spin on flags; hpack not reused until after barriers
    }
}

// ---------------- final projection ----------------
__global__ __launch_bounds__(256) void projection_kernel(const unsigned short* __restrict__ h2h,
                                                         const unsigned short* __restrict__ xcat,
                                                         const unsigned short* __restrict__ wpb,
                                                         const float* __restrict__ bp,
                                                         float* __restrict__ out) {
    int t = blockIdx.x;
    int tid = threadIdx.x;
    int lane = tid & 63, wid = tid >> 6;
    int l15 = lane & 15, quad = lane >> 4;
    int kblk = quad * 8;
    #pragma unroll
    for (int i = 0; i < 3; i++) {
        int tt = wid + i * 4;
        if (tt >= 10) break;          // 2 Mt x 5 Nt tiles
        int Mt = tt & 1, Nt = tt >> 1;
        f32x4 acc = {0.f, 0.f, 0.f, 0.f};
        int b_row = Mt * 16 + l15;
        const unsigned short* h2row = h2h + (size_t)(t * BB + b_row) * HH + kblk;
        const unsigned short* brow = wpb + (size_t)(Nt * 16 + l15) * KP + kblk;
        #pragma unroll
        for (int kk = 0; kk < 32; kk++) {
            f16x8 a = ldg8(h2row + kk * 32);
            f16x8 b = ldg8(brow + kk * 32);
            acc = __builtin_amdgcn_mfma_f32_16x16x32_f16(a, b, acc, 0, 0, 0);
        }
        const unsigned short* drow = xcat + (size_t)(t * BB + b_row) * XK + PRE + kblk;
        #pragma unroll
        for (int kk = 0; kk < 17; kk++) {
            f16x8 a = ldg8(drow + kk * 32);
            f16x8 b = ldg8(brow + HH + kk * 32);
            acc = __builtin_amdgcn_mfma_f32_16x16x32_f16(a, b, acc, 0, 0, 0);
        }
        int mel = Nt * 16 + l15;
        float bpv = bp[mel];
        #pragma unroll
        for (int r = 0; r < 4; r++) {
            int b = Mt * 16 + quad * 4 + r;
            out[(size_t)b * 64000 + mel * 800 + t] = acc[r] + bpv;
        }
    }
}

// ---------------- launch ----------------
extern "C" void kernel_launch(void* const* d_in, const int* in_sizes, int n_in,
                              void* d_out, int out_size, void* d_ws, size_t ws_size,
                              hipStream_t stream) {
    (void)in_sizes; (void)n_in; (void)out_size;
    const float* dur  = (const float*)d_in[0];
    const float* din  = (const float*)d_in[1];
    const float* W1   = (const float*)d_in[3];
    const float* W2   = (const float*)d_in[4];
    const float* Wih1 = (const float*)d_in[5];
    const float* Whh1 = (const float*)d_in[6];
    const float* b1   = (const float*)d_in[7];
    const float* g1   = (const float*)d_in[8];
    const float* be1  = (const float*)d_in[9];
    const float* Wih2 = (const float*)d_in[10];
    const float* Whh2 = (const float*)d_in[11];
    const float* b2   = (const float*)d_in[12];
    const float* g2   = (const float*)d_in[13];
    const float* be2  = (const float*)d_in[14];
    const float* Wp   = (const float*)d_in[15];
    const float* bp   = (const float*)d_in[16];
    const float* pm1  = (const float*)d_in[17];
    const float* pm2  = (const float*)d_in[18];
    const float* dm1  = (const float*)d_in[19];
    const float* dm2  = (const float*)d_in[20];
    float* out = (float*)d_out;
    char* ws = (char*)d_ws;
    if (ws_size < WS_NEEDED) return;

    unsigned short* wih1b = (unsigned short*)(ws + OFF_WIH1B);
    unsigned short* whh1b = (unsigned short*)(ws + OFF_WHH1B);
    unsigned short* wih2b = (unsigned short*)(ws + OFF_WIH2B);
    unsigned short* whh2b = (unsigned short*)(ws + OFF_WHH2B);
    unsigned short* wpb   = (unsigned short*)(ws + OFF_WPB);
    unsigned short* w1b   = (unsigned short*)(ws + OFF_W1B);
    unsigned short* w2b   = (unsigned short*)(ws + OFF_W2B);
    unsigned short* xcat  = (unsigned short*)(ws + OFF_XCAT);
    unsigned short* x1b   = (unsigned short*)(ws + OFF_X1);
    unsigned short* h1h   = (unsigned short*)(ws + OFF_H1H);
    unsigned short* h2h   = (unsigned short*)(ws + OFF_H2H);
    float* part1 = (float*)(ws + OFF_PART1);
    float* part2 = (float*)(ws + OFF_PART2);
    int* flags   = (int*)(ws + OFF_FLAGS);

    hipMemsetAsync(flags, 0, FLAG_BYTES, stream);

    int thr = 256;
    cvt_kernel<<<4096, thr, 0, stream>>>(Wih1, wih1b, G4 * XK);
    cvt_kernel<<<4096, thr, 0, stream>>>(Whh1, whh1b, G4 * HH);
    cvt_kernel<<<4096, thr, 0, stream>>>(Wih2, wih2b, G4 * HH);
    cvt_kernel<<<4096, thr, 0, stream>>>(Whh2, whh2b, G4 * HH);
    cvt_kernel<<<512,  thr, 0, stream>>>(Wp, wpb, NM * KP);
    cvt_w1_kernel<<<(256 * 96 + 255) / 256, thr, 0, stream>>>(W1, w1b);
    cvt_kernel<<<256,  thr, 0, stream>>>(W2, w2b, 256 * 256);

    prenet1_kernel<<<TT, thr, 0, stream>>>(din, w1b, pm1, x1b);
    prenet2_kernel<<<TT, thr, 0, stream>>>(x1b, w2b, pm2, xcat);
    pack_dur_kernel<<<8192, thr, 0, stream>>>(dur, xcat);

    hipFuncSetAttribute((const void*)persistent_kernel,
                        hipFuncAttributeMaxDynamicSharedMemorySize, LDS_TOTAL);
    persistent_kernel<<<256, thr, LDS_TOTAL, stream>>>(
        xcat, wih1b, whh1b, wih2b, whh2b,
        b1, g1, be1, b2, g2, be2, dm1, dm2,
        h1h, h2h, part1, part2, flags);

    projection_kernel<<<TT, thr, 0, stream>>>(h2h, xcat, wpb, bp, out);
}

// Round 4
// 15563.011 us; speedup vs baseline: 1.8524x; 1.2964x over previous
//
#include <hip/hip_runtime.h>

// ---------------- constants ----------------
#define TT 800
#define BB 32
#define HH 1024
#define G4 4096
#define PRE 256
#define DUR 544
#define XK 800            // PRE + DUR
#define KA 1824           // XK + HH
#define KB 2048           // HH + HH
#define NM 80
#define KP 1568           // HH + DUR

#define SA 1864           // LDS row stride (fp16 elems) for chain-A weights
#define SB 2056           // chain-B
#define SA1 104           // prenet1 dec LDS stride

// ws offsets (bytes)
#define OFF_WIH1B  0ull
#define OFF_WHH1B  6553600ull
#define OFF_WIH2B  14942208ull
#define OFF_WHH2B  23330816ull
#define OFF_WPB    31719424ull
#define OFF_W1B    31970304ull
#define OFF_W2B    32019456ull
#define OFF_XCAT   32150528ull
#define OFF_X1     73110528ull
#define OFF_H1H    86217728ull
#define OFF_H2H    138646528ull
#define OFF_PART1  191075328ull
#define OFF_PART2  191337472ull
#define OFF_FLAGS  191599616ull
#define FLAG_BYTES 217600ull
#define WS_NEEDED  (OFF_FLAGS + FLAG_BYTES)

// dynamic LDS layout for persistent kernel
#define LDS_SLAB_OFF  131584   // float[4][32*33] partial-C slabs (one per wave)
#define LDS_STAT_OFF  148480   // float[64]
#define LDS_RED_OFF   148736   // float[256] (reducer scratch)
#define LDS_HPK_OFF   149760   // ushort[256] h repack
#define LDS_TOTAL     150272

typedef __attribute__((ext_vector_type(8))) _Float16 f16x8;
typedef __attribute__((ext_vector_type(4))) float f32x4;
typedef unsigned long long ull;

__device__ __forceinline__ unsigned short f2h(float f) {
    _Float16 h = (_Float16)f;   // v_cvt_f16_f32, RNE
    return __builtin_bit_cast(unsigned short, h);
}
__device__ __forceinline__ float sigf(float x) { return 1.f / (1.f + __expf(-x)); }
__device__ __forceinline__ float tanh_fast(float x) { return 1.f - 2.f / (__expf(2.f * x) + 1.f); }

__device__ __forceinline__ f16x8 ldg8(const unsigned short* p) {
    return *reinterpret_cast<const f16x8*>(p);
}

// coherent (IF$-direct) 16B load: 2x 8B relaxed agent atomics
__device__ __forceinline__ f16x8 ld_h16(const ull* p) {
    union { ull u[2]; f16x8 v; } x;
    x.u[0] = __hip_atomic_load(p,     __ATOMIC_RELAXED, __HIP_MEMORY_SCOPE_AGENT);
    x.u[1] = __hip_atomic_load(p + 1, __ATOMIC_RELAXED, __HIP_MEMORY_SCOPE_AGENT);
    return x.v;
}
__device__ __forceinline__ float ld_cf(const float* p) {
    return __hip_atomic_load(p, __ATOMIC_RELAXED, __HIP_MEMORY_SCOPE_AGENT);
}
__device__ __forceinline__ void st_cf(float* p, float v) {
    __hip_atomic_store(p, v, __ATOMIC_RELAXED, __HIP_MEMORY_SCOPE_AGENT);
}

__device__ __forceinline__ void spin_until(int* p, int target) {
    while (__hip_atomic_load(p, __ATOMIC_RELAXED, __HIP_MEMORY_SCOPE_AGENT) < target)
        __builtin_amdgcn_s_sleep(1);
}

// wait vmcnt(0) only (expcnt=7, lgkmcnt=15 untouched)
#define WAIT_VM0() __builtin_amdgcn_s_waitcnt(0x0F70)

// ---------------- conversion kernels ----------------
__global__ void cvt_kernel(const float* __restrict__ src, unsigned short* __restrict__ dst, int n) {
    for (int i = blockIdx.x * blockDim.x + threadIdx.x; i < n; i += gridDim.x * blockDim.x)
        dst[i] = f2h(src[i]);
}

__global__ void cvt_w1_kernel(const float* __restrict__ w1, unsigned short* __restrict__ dst) {
    int i = blockIdx.x * blockDim.x + threadIdx.x;
    if (i >= 256 * 96) return;
    int j = i / 96, m = i % 96;
    dst[i] = (m < 80) ? f2h(w1[j * 80 + m]) : 0;
}

__global__ void pack_dur_kernel(const float* __restrict__ dur, unsigned short* __restrict__ xcat) {
    int n = TT * BB * DUR;
    for (int i = blockIdx.x * blockDim.x + threadIdx.x; i < n; i += gridDim.x * blockDim.x) {
        int t = i / (BB * DUR);
        int r = i % (BB * DUR);
        int b = r / DUR, e = r % DUR;
        xcat[(size_t)(t * BB + b) * XK + PRE + e] = f2h(dur[(size_t)b * (TT * DUR) + t * DUR + e]);
    }
}

// ---------------- prenet layer 1 ----------------
__global__ __launch_bounds__(256) void prenet1_kernel(const float* __restrict__ din,
                                                      const unsigned short* __restrict__ w1b,
                                                      const float* __restrict__ pm1,
                                                      unsigned short* __restrict__ x1b) {
    int t = blockIdx.x;
    __shared__ unsigned short decs[32 * SA1];
    int tid = threadIdx.x;
    for (int idx = tid; idx < 32 * 96; idx += 256) {
        int b = idx / 96, m = idx % 96;
        float v = (m < 80 && t > 0) ? din[(size_t)b * 64000 + m * 800 + (t - 1)] : 0.f;
        decs[b * SA1 + m] = f2h(v);
    }
    __syncthreads();
    int lane = tid & 63, wid = tid >> 6;
    int l15 = lane & 15, quad = lane >> 4;
    int kblk = quad * 8;
    #pragma unroll
    for (int i = 0; i < 8; i++) {
        int tt = wid * 8 + i;
        int Mt = tt & 1, Nt = tt >> 1;
        f32x4 acc = {0.f, 0.f, 0.f, 0.f};
        int arow = (Mt * 16 + l15) * SA1 + kblk;
        int brow = (Nt * 16 + l15) * 96 + kblk;
        #pragma unroll
        for (int kk = 0; kk < 3; kk++) {
            f16x8 a = *reinterpret_cast<const f16x8*>(&decs[arow + kk * 32]);
            f16x8 b = ldg8(w1b + brow + kk * 32);
            acc = __builtin_amdgcn_mfma_f32_16x16x32_f16(a, b, acc, 0, 0, 0);
        }
        int n = Nt * 16 + l15;
        #pragma unroll
        for (int r = 0; r < 4; r++) {
            int b_row = Mt * 16 + quad * 4 + r;
            float v = fmaxf(acc[r], 0.f) * pm1[(size_t)(t * BB + b_row) * PRE + n];
            x1b[(size_t)(t * BB + b_row) * PRE + n] = f2h(v);
        }
    }
}

// ---------------- prenet layer 2 ----------------
__global__ __launch_bounds__(256) void prenet2_kernel(const unsigned short* __restrict__ x1b,
                                                      const unsigned short* __restrict__ w2b,
                                                      const float* __restrict__ pm2,
                                                      unsigned short* __restrict__ xcat) {
    int t = blockIdx.x;
    int tid = threadIdx.x;
    int lane = tid & 63, wid = tid >> 6;
    int l15 = lane & 15, quad = lane >> 4;
    int kblk = quad * 8;
    #pragma unroll
    for (int i = 0; i < 8; i++) {
        int tt = wid * 8 + i;
        int Mt = tt & 1, Nt = tt >> 1;
        f32x4 acc = {0.f, 0.f, 0.f, 0.f};
        const unsigned short* arow = x1b + (size_t)(t * BB + Mt * 16 + l15) * PRE + kblk;
        const unsigned short* brow = w2b + (size_t)(Nt * 16 + l15) * PRE + kblk;
        #pragma unroll
        for (int kk = 0; kk < 8; kk++) {
            f16x8 a = ldg8(arow + kk * 32);
            f16x8 b = ldg8(brow + kk * 32);
            acc = __builtin_amdgcn_mfma_f32_16x16x32_f16(a, b, acc, 0, 0, 0);
        }
        int n = Nt * 16 + l15;
        #pragma unroll
        for (int r = 0; r < 4; r++) {
            int b_row = Mt * 16 + quad * 4 + r;
            float v = fmaxf(acc[r], 0.f) * pm2[(size_t)(t * BB + b_row) * PRE + n];
            xcat[(size_t)(t * BB + b_row) * XK + n] = f2h(v);
        }
    }
}

// ---------------- persistent recurrence kernel ----------------
// Waves are K-split: wave kid takes kk = kid, kid+4, ... and accumulates a
// PARTIAL 32x32 gate tile into its own LDS slab; a sum pass adds 4 slabs.
__global__ __launch_bounds__(256, 1) void persistent_kernel(
    const unsigned short* __restrict__ xcat,
    const unsigned short* __restrict__ wih1b, const unsigned short* __restrict__ whh1b,
    const unsigned short* __restrict__ wih2b, const unsigned short* __restrict__ whh2b,
    const float* __restrict__ b1, const float* __restrict__ g1, const float* __restrict__ be1,
    const float* __restrict__ b2, const float* __restrict__ g2, const float* __restrict__ be2,
    const float* __restrict__ dm1, const float* __restrict__ dm2,
    unsigned short* __restrict__ h1h, unsigned short* __restrict__ h2h,
    float* __restrict__ part1, float* __restrict__ part2,
    int* __restrict__ flags) {

    extern __shared__ char smem[];
    unsigned short* W = (unsigned short*)smem;
    float* slab = (float*)(smem + LDS_SLAB_OFF);    // [4][32*33]
    float* stat = (float*)(smem + LDS_STAT_OFF);    // [64]
    float* red  = (float*)(smem + LDS_RED_OFF);     // [256]
    unsigned short* hpack = (unsigned short*)(smem + LDS_HPK_OFF); // [256]

    int wg = blockIdx.x;
    bool isA = wg < 128;
    int w = isA ? wg : wg - 128;
    int tid = threadIdx.x;
    int lane = tid & 63;
    int kid = tid >> 6;              // wave id == K-split id
    int l15 = lane & 15, quad = lane >> 4;
    int koff = quad * 8;

    // flags
    int* r_h1     = flags + 800;
    int* gbase    = flags + 3200;
    int* r_stats  = isA ? flags : (flags + 1600);   // tree->16, reducer->17
    int* r_hmy    = isA ? (flags + 800) : (flags + 2400);
    int* g_stats  = isA ? gbase : (gbase + 25600);
    int* g_hmy    = isA ? (gbase + 12800) : (gbase + 38400);
    float* part   = isA ? part1 : part2;            // [4][8192] partials
    float* statg  = part + 4 * 8192;                // [4][64] reduced stats
    int gidx = w >> 3;
    bool isRed = (w == 0);

    // load weight slice into LDS
    if (isA) {
        for (int idx = tid; idx < 32 * KA; idx += 256) {
            int r = idx / KA, k = idx % KA;
            int grow = (r >> 3) * HH + w * 8 + (r & 7);
            W[r * SA + k] = (k < XK) ? wih1b[(size_t)grow * XK + k]
                                     : whh1b[(size_t)grow * HH + (k - XK)];
        }
    } else {
        for (int idx = tid; idx < 32 * KB; idx += 256) {
            int r = idx / KB, k = idx % KB;
            int grow = (r >> 3) * HH + w * 8 + (r & 7);
            W[r * SB + k] = (k < HH) ? wih2b[(size_t)grow * HH + k]
                                     : whh2b[(size_t)grow * HH + (k - HH)];
        }
    }

    // sum-pass constants: thread owns gate-local row n_s, batches ms..ms+3
    int n_s = tid & 31, ms = (tid >> 5) * 4;
    int gate_ns = (n_s >> 3) * HH + w * 8 + (n_s & 7);
    float bsum = isA ? b1[gate_ns] : b2[gate_ns];

    // pointwise constants
    int pb = tid & 31, pu = tid >> 5;
    int unit = w * 8 + pu;
    float g1v[4], bev[4];
    {
        const float* gs = isA ? g1 : g2;
        const float* bs = isA ? be1 : be2;
        #pragma unroll
        for (int g = 0; g < 4; g++) { g1v[g] = gs[g * HH + unit]; bev[g] = bs[g * HH + unit]; }
    }
    const float* dms = isA ? dm1 : dm2;
    unsigned short* hout = isA ? h1h : h2h;
    float* myslab = slab + kid * (32 * 33);
    int stride_slab = 33;
    float creg = 0.f;
    __syncthreads();

    for (int t = 0; t < TT; t++) {
        int slot = t & 3;
        f32x4 a00 = {0,0,0,0}, a01 = {0,0,0,0}, a10 = {0,0,0,0}, a11 = {0,0,0,0};

        if (isA) {
            // x-part: plain cached loads, no dependency on h1[t-1]
            const unsigned short* xb = xcat + (size_t)(t * BB) * XK;
            for (int kk = kid; kk < 25; kk += 4) {
                int k0 = kk * 32 + koff;
                f16x8 x0 = ldg8(xb + (size_t)(l15)      * XK + k0);
                f16x8 x1 = ldg8(xb + (size_t)(16 + l15) * XK + k0);
                f16x8 w0 = *(const f16x8*)&W[(l15)      * SA + k0];
                f16x8 w1 = *(const f16x8*)&W[(16 + l15) * SA + k0];
                a00 = __builtin_amdgcn_mfma_f32_16x16x32_f16(x0, w0, a00, 0, 0, 0);
                a01 = __builtin_amdgcn_mfma_f32_16x16x32_f16(x0, w1, a01, 0, 0, 0);
                a10 = __builtin_amdgcn_mfma_f32_16x16x32_f16(x1, w0, a10, 0, 0, 0);
                a11 = __builtin_amdgcn_mfma_f32_16x16x32_f16(x1, w1, a11, 0, 0, 0);
            }
            if (t > 0) {
                if (tid == 0) spin_until(&r_hmy[t - 1], 16);
                __syncthreads();
                const unsigned short* hb = h1h + (size_t)((t - 1) * BB) * HH;
                for (int kk = kid; kk < 32; kk += 4) {
                    int k0 = kk * 32 + koff;
                    f16x8 x0 = ld_h16((const ull*)(hb + (size_t)(l15)      * HH + k0));
                    f16x8 x1 = ld_h16((const ull*)(hb + (size_t)(16 + l15) * HH + k0));
                    f16x8 w0 = *(const f16x8*)&W[(l15)      * SA + XK + k0];
                    f16x8 w1 = *(const f16x8*)&W[(16 + l15) * SA + XK + k0];
                    a00 = __builtin_amdgcn_mfma_f32_16x16x32_f16(x0, w0, a00, 0, 0, 0);
                    a01 = __builtin_amdgcn_mfma_f32_16x16x32_f16(x0, w1, a01, 0, 0, 0);
                    a10 = __builtin_amdgcn_mfma_f32_16x16x32_f16(x1, w0, a10, 0, 0, 0);
                    a11 = __builtin_amdgcn_mfma_f32_16x16x32_f16(x1, w1, a11, 0, 0, 0);
                }
            }
        } else {
            if (t > 0) {
                if (tid == 0) spin_until(&r_hmy[t - 1], 16);
                __syncthreads();
                const unsigned short* hb = h2h + (size_t)((t - 1) * BB) * HH;
                for (int kk = kid; kk < 32; kk += 4) {
                    int k0 = kk * 32 + koff;
                    f16x8 x0 = ld_h16((const ull*)(hb + (size_t)(l15)      * HH + k0));
                    f16x8 x1 = ld_h16((const ull*)(hb + (size_t)(16 + l15) * HH + k0));
                    f16x8 w0 = *(const f16x8*)&W[(l15)      * SB + HH + k0];
                    f16x8 w1 = *(const f16x8*)&W[(16 + l15) * SB + HH + k0];
                    a00 = __builtin_amdgcn_mfma_f32_16x16x32_f16(x0, w0, a00, 0, 0, 0);
                    a01 = __builtin_amdgcn_mfma_f32_16x16x32_f16(x0, w1, a01, 0, 0, 0);
                    a10 = __builtin_amdgcn_mfma_f32_16x16x32_f16(x1, w0, a10, 0, 0, 0);
                    a11 = __builtin_amdgcn_mfma_f32_16x16x32_f16(x1, w1, a11, 0, 0, 0);
                }
            }
            if (tid == 0) spin_until(&r_h1[t], 16);
            __syncthreads();
            const unsigned short* hb = h1h + (size_t)(t * BB) * HH;
            for (int kk = kid; kk < 32; kk += 4) {
                int k0 = kk * 32 + koff;
                f16x8 x0 = ld_h16((const ull*)(hb + (size_t)(l15)      * HH + k0));
                f16x8 x1 = ld_h16((const ull*)(hb + (size_t)(16 + l15) * HH + k0));
                f16x8 w0 = *(const f16x8*)&W[(l15)      * SB + k0];
                f16x8 w1 = *(const f16x8*)&W[(16 + l15) * SB + k0];
                a00 = __builtin_amdgcn_mfma_f32_16x16x32_f16(x0, w0, a00, 0, 0, 0);
                a01 = __builtin_amdgcn_mfma_f32_16x16x32_f16(x0, w1, a01, 0, 0, 0);
                a10 = __builtin_amdgcn_mfma_f32_16x16x32_f16(x1, w0, a10, 0, 0, 0);
                a11 = __builtin_amdgcn_mfma_f32_16x16x32_f16(x1, w1, a11, 0, 0, 0);
            }
        }

        // epilogue: each wave writes its partial C tile into its own slab
        // n = Nt*16 + l15, m = Mt*16 + quad*4 + r
        #pragma unroll
        for (int r = 0; r < 4; r++) {
            int m0 = quad * 4 + r;
            myslab[(l15)      * stride_slab + m0]      = a00[r];
            myslab[(16 + l15) * stride_slab + m0]      = a01[r];
            myslab[(l15)      * stride_slab + 16 + m0] = a10[r];
            myslab[(16 + l15) * stride_slab + 16 + m0] = a11[r];
        }
        __syncthreads();

        // sum pass: add 4 slabs + bias, write into slab 0
        {
            int base = n_s * stride_slab + ms;
            #pragma unroll
            for (int j = 0; j < 4; j++) {
                float v = slab[base + j] + slab[1056 + base + j]
                        + slab[2112 + base + j] + slab[3168 + base + j] + bsum;
                slab[base + j] = v;
            }
        }
        __syncthreads();

        // LN partials (wave 0) -> coherent store
        if (tid < 64) {
            int b = tid & 31, st = tid >> 5;
            float s = 0.f;
            #pragma unroll 8
            for (int n = 0; n < 32; n++) { float v = slab[n * stride_slab + b]; s += st ? v * v : v; }
            st_cf(&part[slot * 8192 + w * 64 + tid], s);
        }
        if (tid == 0) {
            WAIT_VM0();
            int old = __hip_atomic_fetch_add(&g_stats[t * 16 + gidx], 1,
                                             __ATOMIC_RELAXED, __HIP_MEMORY_SCOPE_AGENT);
            if (old == 7)
                __hip_atomic_fetch_add(&r_stats[t], 1,
                                       __ATOMIC_RELAXED, __HIP_MEMORY_SCOPE_AGENT);
        }

        // reducer WG: gather 128x64 partials, publish 64 stats, bump 16->17
        if (isRed) {
            if (tid == 0) spin_until(&r_stats[t], 16);
            __syncthreads();
            {
                const float* pp = part + slot * 8192;
                float s = 0.f;
                int wp = tid >> 6, j = tid & 63;
                #pragma unroll
                for (int i = 0; i < 32; i++)
                    s += ld_cf(&pp[(wp + i * 4) * 64 + j]);
                red[tid] = s;
            }
            __syncthreads();
            if (tid < 64)
                st_cf(&statg[slot * 64 + tid],
                      red[tid] + red[64 + tid] + red[128 + tid] + red[192 + tid]);
            if (tid == 0) {
                WAIT_VM0();
                __hip_atomic_fetch_add(&r_stats[t], 1,
                                       __ATOMIC_RELAXED, __HIP_MEMORY_SCOPE_AGENT);
            }
        }

        // all WGs: wait for stats, load 64 floats
        if (tid == 0) spin_until(&r_stats[t], 17);
        __syncthreads();
        if (tid < 64) stat[tid] = ld_cf(&statg[slot * 64 + tid]);
        __syncthreads();

        // pointwise: LN -> LSTM cell -> dropout -> repack h into LDS
        {
            float mean = stat[pb] * (1.f / 4096.f);
            float var = stat[32 + pb] * (1.f / 4096.f) - mean * mean;
            float rs = rsqrtf(var + 1e-5f);
            float z[4];
            #pragma unroll
            for (int g = 0; g < 4; g++)
                z[g] = (slab[(g * 8 + pu) * stride_slab + pb] - mean) * rs * g1v[g] + bev[g];
            float iv = sigf(z[0]), fv = sigf(z[1]), gv = tanh_fast(z[2]), ov = sigf(z[3]);
            creg = fv * creg + iv * gv;
            float h = ov * tanh_fast(creg);
            h *= dms[(size_t)(t * BB + pb) * HH + unit];
            hpack[pb * 8 + pu] = f2h(h);
        }
        __syncthreads();

        // publish h: wave 0 stores 64x 8B coherent, then signals
        if (tid < 64) {
            int b = tid >> 1, half = tid & 1;
            ull v = *(const ull*)((const char*)hpack + tid * 8);
            __hip_atomic_store((ull*)(hout + (size_t)(t * BB + b) * HH + w * 8 + half * 4),
                               v, __ATOMIC_RELAXED, __HIP_MEMORY_SCOPE_AGENT);
        }
        if (tid == 0) {
            WAIT_VM0();
            int old = __hip_atomic_fetch_add(&g_hmy[t * 16 + gidx], 1,
                                             __ATOMIC_RELAXED, __HIP_MEMORY_SCOPE_AGENT);
            if (old == 7)
                __hip_atomic_fetch_add(&r_hmy[t], 1,
                                       __ATOMIC_RELAXED, __HIP_MEMORY_SCOPE_AGENT);
        }
    }
}

// ---------------- final projection ----------------
__global__ __launch_bounds__(256) void projection_kernel(const unsigned short* __restrict__ h2h,
                                                         const unsigned short* __restrict__ xcat,
                                                         const unsigned short* __restrict__ wpb,
                                                         const float* __restrict__ bp,
                                                         float* __restrict__ out) {
    int t = blockIdx.x;
    int tid = threadIdx.x;
    int lane = tid & 63, wid = tid >> 6;
    int l15 = lane & 15, quad = lane >> 4;
    int kblk = quad * 8;
    #pragma unroll
    for (int i = 0; i < 3; i++) {
        int tt = wid + i * 4;
        if (tt >= 10) break;          // 2 Mt x 5 Nt tiles
        int Mt = tt & 1, Nt = tt >> 1;
        f32x4 acc = {0.f, 0.f, 0.f, 0.f};
        int b_row = Mt * 16 + l15;
        const unsigned short* h2row = h2h + (size_t)(t * BB + b_row) * HH + kblk;
        const unsigned short* brow = wpb + (size_t)(Nt * 16 + l15) * KP + kblk;
        #pragma unroll
        for (int kk = 0; kk < 32; kk++) {
            f16x8 a = ldg8(h2row + kk * 32);
            f16x8 b = ldg8(brow + kk * 32);
            acc = __builtin_amdgcn_mfma_f32_16x16x32_f16(a, b, acc, 0, 0, 0);
        }
        const unsigned short* drow = xcat + (size_t)(t * BB + b_row) * XK + PRE + kblk;
        #pragma unroll
        for (int kk = 0; kk < 17; kk++) {
            f16x8 a = ldg8(drow + kk * 32);
            f16x8 b = ldg8(brow + HH + kk * 32);
            acc = __builtin_amdgcn_mfma_f32_16x16x32_f16(a, b, acc, 0, 0, 0);
        }
        int mel = Nt * 16 + l15;
        float bpv = bp[mel];
        #pragma unroll
        for (int r = 0; r < 4; r++) {
            int b = Mt * 16 + quad * 4 + r;
            out[(size_t)b * 64000 + mel * 800 + t] = acc[r] + bpv;
        }
    }
}

// ---------------- launch ----------------
extern "C" void kernel_launch(void* const* d_in, const int* in_sizes, int n_in,
                              void* d_out, int out_size, void* d_ws, size_t ws_size,
                              hipStream_t stream) {
    (void)in_sizes; (void)n_in; (void)out_size;
    const float* dur  = (const float*)d_in[0];
    const float* din  = (const float*)d_in[1];
    const float* W1   = (const float*)d_in[3];
    const float* W2   = (const float*)d_in[4];
    const float* Wih1 = (const float*)d_in[5];
    const float* Whh1 = (const float*)d_in[6];
    const float* b1   = (const float*)d_in[7];
    const float* g1   = (const float*)d_in[8];
    const float* be1  = (const float*)d_in[9];
    const float* Wih2 = (const float*)d_in[10];
    const float* Whh2 = (const float*)d_in[11];
    const float* b2   = (const float*)d_in[12];
    const float* g2   = (const float*)d_in[13];
    const float* be2  = (const float*)d_in[14];
    const float* Wp   = (const float*)d_in[15];
    const float* bp   = (const float*)d_in[16];
    const float* pm1  = (const float*)d_in[17];
    const float* pm2  = (const float*)d_in[18];
    const float* dm1  = (const float*)d_in[19];
    const float* dm2  = (const float*)d_in[20];
    float* out = (float*)d_out;
    char* ws = (char*)d_ws;
    if (ws_size < WS_NEEDED) return;

    unsigned short* wih1b = (unsigned short*)(ws + OFF_WIH1B);
    unsigned short* whh1b = (unsigned short*)(ws + OFF_WHH1B);
    unsigned short* wih2b = (unsigned short*)(ws + OFF_WIH2B);
    unsigned short* whh2b = (unsigned short*)(ws + OFF_WHH2B);
    unsigned short* wpb   = (unsigned short*)(ws + OFF_WPB);
    unsigned short* w1b   = (unsigned short*)(ws + OFF_W1B);
    unsigned short* w2b   = (unsigned short*)(ws + OFF_W2B);
    unsigned short* xcat  = (unsigned short*)(ws + OFF_XCAT);
    unsigned short* x1b   = (unsigned short*)(ws + OFF_X1);
    unsigned short* h1h   = (unsigned short*)(ws + OFF_H1H);
    unsigned short* h2h   = (unsigned short*)(ws + OFF_H2H);
    float* part1 = (float*)(ws + OFF_PART1);
    float* part2 = (float*)(ws + OFF_PART2);
    int* flags   = (int*)(ws + OFF_FLAGS);

    hipMemsetAsync(flags, 0, FLAG_BYTES, stream);

    int thr = 256;
    cvt_kernel<<<4096, thr, 0, stream>>>(Wih1, wih1b, G4 * XK);
    cvt_kernel<<<4096, thr, 0, stream>>>(Whh1, whh1b, G4 * HH);
    cvt_kernel<<<4096, thr, 0, stream>>>(Wih2, wih2b, G4 * HH);
    cvt_kernel<<<4096, thr, 0, stream>>>(Whh2, whh2b, G4 * HH);
    cvt_kernel<<<512,  thr, 0, stream>>>(Wp, wpb, NM * KP);
    cvt_w1_kernel<<<(256 * 96 + 255) / 256, thr, 0, stream>>>(W1, w1b);
    cvt_kernel<<<256,  thr, 0, stream>>>(W2, w2b, 256 * 256);

    prenet1_kernel<<<TT, thr, 0, stream>>>(din, w1b, pm1, x1b);
    prenet2_kernel<<<TT, thr, 0, stream>>>(x1b, w2b, pm2, xcat);
    pack_dur_kernel<<<8192, thr, 0, stream>>>(dur, xcat);

    hipFuncSetAttribute((const void*)persistent_kernel,
                        hipFuncAttributeMaxDynamicSharedMemorySize, LDS_TOTAL);
    persistent_kernel<<<256, thr, LDS_TOTAL, stream>>>(
        xcat, wih1b, whh1b, wih2b, whh2b,
        b1, g1, be1, b2, g2, be2, dm1, dm2,
        h1h, h2h, part1, part2, flags);

    projection_kernel<<<TT, thr, 0, stream>>>(h2h, xcat, wpb, bp, out);
}